// Round 1
// baseline (499.812 us; speedup 1.0000x reference)
//
#include <hip/hip_runtime.h>

#define B_   2
#define N_   2048
#define C_   1024
#define H_   16
#define D_   64
#define HID_ 4096
#define M_   (B_ * N_)   // 4096 rows

typedef __attribute__((ext_vector_type(8))) short bf16x8;  // 8 bf16 = 4 VGPRs
typedef __attribute__((ext_vector_type(4))) float f32x4;

__device__ __forceinline__ unsigned short f2bf(float f) {
  unsigned int u = __builtin_bit_cast(unsigned int, f);
  u += 0x7fffu + ((u >> 16) & 1u);   // RNE
  return (unsigned short)(u >> 16);
}

// ---------------- LayerNorm (fp32 in -> bf16 out), one block per row ----------------
__global__ __launch_bounds__(256) void ln_kernel(const float* __restrict__ x,
                                                 const float* __restrict__ g,
                                                 const float* __restrict__ bta,
                                                 unsigned short* __restrict__ out) {
  int row = blockIdx.x;
  int tid = threadIdx.x;
  const float4 v = *(const float4*)(x + (size_t)row * C_ + tid * 4);
  float s1 = v.x + v.y + v.z + v.w;
  float s2 = v.x * v.x + v.y * v.y + v.z * v.z + v.w * v.w;
#pragma unroll
  for (int m = 1; m < 64; m <<= 1) { s1 += __shfl_xor(s1, m); s2 += __shfl_xor(s2, m); }
  __shared__ float red[2][4];
  int w = tid >> 6, lane = tid & 63;
  if (lane == 0) { red[0][w] = s1; red[1][w] = s2; }
  __syncthreads();
  s1 = red[0][0] + red[0][1] + red[0][2] + red[0][3];
  s2 = red[1][0] + red[1][1] + red[1][2] + red[1][3];
  float mu  = s1 * (1.0f / C_);
  float var = s2 * (1.0f / C_) - mu * mu;
  float rs  = rsqrtf(var + 1e-5f);
  const float4 gv = *(const float4*)(g + tid * 4);
  const float4 bv = *(const float4*)(bta + tid * 4);
  ushort4 o;
  o.x = f2bf((v.x - mu) * rs * gv.x + bv.x);
  o.y = f2bf((v.y - mu) * rs * gv.y + bv.y);
  o.z = f2bf((v.z - mu) * rs * gv.z + bv.z);
  o.w = f2bf((v.w - mu) * rs * gv.w + bv.w);
  *(ushort4*)(out + (size_t)row * C_ + tid * 4) = o;
}

// ---------------- Weight transpose + fp32->bf16: W[K][N] -> Wt[N][K] ----------------
__global__ __launch_bounds__(256) void wtrans_kernel(const float* __restrict__ W,
                                                     unsigned short* __restrict__ Wt,
                                                     int K, int N) {
  __shared__ float t[32][33];
  int n0 = blockIdx.x * 32, k0 = blockIdx.y * 32;
  int tx = threadIdx.x, ty = threadIdx.y;  // 32 x 8
#pragma unroll
  for (int j = 0; j < 4; j++)
    t[ty + j * 8][tx] = W[(size_t)(k0 + ty + j * 8) * N + n0 + tx];
  __syncthreads();
#pragma unroll
  for (int j = 0; j < 4; j++)
    Wt[(size_t)(n0 + ty + j * 8) * K + k0 + tx] = f2bf(t[tx][ty + j * 8]);
}

// ---------------- bf16 MFMA GEMM: C[M][N] = A[M][K] @ W[K][N]  (Wt = W^T) -----------
// MODE 0: scatter to q(*0.125)/k/v bf16 [B,H,N,D]
// MODE 1: outf = acc + bias + resid (fp32)
// MODE 2: outb0 = bf16(gelu_exact(acc + bias))
template <int MODE>
__global__ __launch_bounds__(256) void gemm_kernel(
    const unsigned short* __restrict__ A,    // [M][K] bf16
    const unsigned short* __restrict__ Wt,   // [N][K] bf16
    const float* __restrict__ bias,
    const float* __restrict__ resid,
    float* __restrict__ outf,
    unsigned short* __restrict__ outb0,
    unsigned short* __restrict__ outb1,
    unsigned short* __restrict__ outb2,
    int M, int N, int K) {
  __shared__ __align__(16) unsigned short As[128][72];  // +8 pad: 2-way-only aliasing
  __shared__ __align__(16) unsigned short Bs[128][72];  // Bs[n][k]
  int tid = threadIdx.x;
  int w = tid >> 6, lane = tid & 63, r = lane & 15, quad = lane >> 4;
  int wr = w >> 1, wc = w & 1;
  int bM = blockIdx.y * 128, bN = blockIdx.x * 128;

  f32x4 acc[4][4];
#pragma unroll
  for (int i = 0; i < 4; i++)
#pragma unroll
    for (int j = 0; j < 4; j++) acc[i][j] = f32x4{0.f, 0.f, 0.f, 0.f};

  for (int k0 = 0; k0 < K; k0 += 64) {
    __syncthreads();
#pragma unroll
    for (int p = 0; p < 4; p++) {
      int idx = p * 256 + tid;
      int rowa = idx >> 3, kc = idx & 7;
      *(uint4*)&As[rowa][kc * 8] = *(const uint4*)(A  + (size_t)(bM + rowa) * K + k0 + kc * 8);
      *(uint4*)&Bs[rowa][kc * 8] = *(const uint4*)(Wt + (size_t)(bN + rowa) * K + k0 + kc * 8);
    }
    __syncthreads();
#pragma unroll
    for (int kk = 0; kk < 64; kk += 32) {
      bf16x8 af[4], bf[4];
#pragma unroll
      for (int mt = 0; mt < 4; mt++)
        af[mt] = *(const bf16x8*)&As[wr * 64 + mt * 16 + r][kk + quad * 8];
#pragma unroll
      for (int nt = 0; nt < 4; nt++)
        bf[nt] = *(const bf16x8*)&Bs[wc * 64 + nt * 16 + r][kk + quad * 8];
#pragma unroll
      for (int mt = 0; mt < 4; mt++)
#pragma unroll
        for (int nt = 0; nt < 4; nt++)
          acc[mt][nt] = __builtin_amdgcn_mfma_f32_16x16x32_bf16(af[mt], bf[nt], acc[mt][nt], 0, 0, 0);
    }
  }

  // Epilogue. D layout: row = quad*4+i, col = r (within 16x16 tile)
#pragma unroll
  for (int mt = 0; mt < 4; mt++) {
#pragma unroll
    for (int nt = 0; nt < 4; nt++) {
#pragma unroll
      for (int i = 0; i < 4; i++) {
        int gm = bM + wr * 64 + mt * 16 + quad * 4 + i;
        int gn = bN + wc * 64 + nt * 16 + r;
        float val = acc[mt][nt][i];
        if (MODE == 0) {
          int s = gn >> 10, c = gn & 1023;
          int hh = c >> 6, d = c & 63;
          int b = gm >> 11, n = gm & 2047;
          size_t di = ((size_t)(b * H_ + hh) * N_ + n) * D_ + d;
          unsigned short bvv = f2bf(s == 0 ? val * 0.125f : val);
          (s == 0 ? outb0 : (s == 1 ? outb1 : outb2))[di] = bvv;
        } else if (MODE == 1) {
          outf[(size_t)gm * N + gn] = val + bias[gn] + resid[(size_t)gm * N + gn];
        } else {
          float t = val + bias[gn];
          float gl = 0.5f * t * (1.0f + erff(t * 0.70710678118f));
          outb0[(size_t)gm * N + gn] = f2bf(gl);
        }
      }
    }
  }
}

// ---------------- Flash attention: q pre-scaled by 1/8; bf16 in, bf16 out ----------
// grid = (B*H) * (N/128); block 256 = 4 waves; wave handles 32 q-rows.
__global__ __launch_bounds__(256) void attn_kernel(const unsigned short* __restrict__ qb,
                                                   const unsigned short* __restrict__ kb,
                                                   const unsigned short* __restrict__ vb,
                                                   unsigned short* __restrict__ ob) {
  __shared__ __align__(16) unsigned short Vt[64][136];     // V^T: [d][key], pad 8
  __shared__ __align__(16) unsigned short Pl[4][32][136];  // per-wave P staging
  int tid = threadIdx.x;
  int w = tid >> 6, lane = tid & 63, r = lane & 15, quad = lane >> 4;
  int bh = blockIdx.x >> 4, qt = blockIdx.x & 15;
  const unsigned short* qh = qb + (size_t)bh * N_ * D_;
  const unsigned short* kh = kb + (size_t)bh * N_ * D_;
  const unsigned short* vh = vb + (size_t)bh * N_ * D_;

  // Q fragments (A-layout): row = tile + r, k = ks*32 + quad*8 + j
  bf16x8 qf[2][2];
#pragma unroll
  for (int mt = 0; mt < 2; mt++)
#pragma unroll
    for (int ks = 0; ks < 2; ks++)
      qf[mt][ks] = *(const bf16x8*)(qh + (size_t)(qt * 128 + w * 32 + mt * 16 + r) * D_ + ks * 32 + quad * 8);

  float mst[2][4], lst[2][4];
  f32x4 oacc[2][4];
#pragma unroll
  for (int mt = 0; mt < 2; mt++)
#pragma unroll
    for (int i = 0; i < 4; i++) { mst[mt][i] = -1e30f; lst[mt][i] = 0.f; }
#pragma unroll
  for (int mt = 0; mt < 2; mt++)
#pragma unroll
    for (int nt = 0; nt < 4; nt++) oacc[mt][nt] = f32x4{0.f, 0.f, 0.f, 0.f};

  for (int t = 0; t < 16; t++) {
    __syncthreads();  // protect Vt from previous-iteration readers
    // stage V transposed: Vt[d][key]
#pragma unroll
    for (int p = 0; p < 4; p++) {
      int idx = p * 256 + tid;
      int key = idx >> 3, dc = idx & 7;
      uint4 raw = *(const uint4*)(vh + (size_t)(t * 128 + key) * D_ + dc * 8);
      const unsigned short* e = (const unsigned short*)&raw;
#pragma unroll
      for (int j = 0; j < 8; j++) Vt[dc * 8 + j][key] = e[j];
    }
    __syncthreads();

    // S = Q K^T (K fragments loaded straight from global, contiguous 16B)
    f32x4 sacc[2][8];
#pragma unroll
    for (int mt = 0; mt < 2; mt++)
#pragma unroll
      for (int nt = 0; nt < 8; nt++) sacc[mt][nt] = f32x4{0.f, 0.f, 0.f, 0.f};
#pragma unroll
    for (int ks = 0; ks < 2; ks++) {
#pragma unroll
      for (int nt = 0; nt < 8; nt++) {
        bf16x8 kf = *(const bf16x8*)(kh + (size_t)(t * 128 + nt * 16 + r) * D_ + ks * 32 + quad * 8);
#pragma unroll
        for (int mt = 0; mt < 2; mt++)
          sacc[mt][nt] = __builtin_amdgcn_mfma_f32_16x16x32_bf16(qf[mt][ks], kf, sacc[mt][nt], 0, 0, 0);
      }
    }

    // online softmax; rows of a quad reduce across its 16 r-lanes
#pragma unroll
    for (int mt = 0; mt < 2; mt++) {
#pragma unroll
      for (int i = 0; i < 4; i++) {
        float tm = sacc[mt][0][i];
#pragma unroll
        for (int nt = 1; nt < 8; nt++) tm = fmaxf(tm, sacc[mt][nt][i]);
#pragma unroll
        for (int m = 1; m < 16; m <<= 1) tm = fmaxf(tm, __shfl_xor(tm, m));
        float mnew  = fmaxf(mst[mt][i], tm);
        float alpha = __expf(mst[mt][i] - mnew);
        mst[mt][i]  = mnew;
        float rs = 0.f;
#pragma unroll
        for (int nt = 0; nt < 8; nt++) {
          float p = __expf(sacc[mt][nt][i] - mnew);
          sacc[mt][nt][i] = p;
          rs += p;
        }
#pragma unroll
        for (int m = 1; m < 16; m <<= 1) rs += __shfl_xor(rs, m);
        lst[mt][i] = lst[mt][i] * alpha + rs;
#pragma unroll
        for (int nt = 0; nt < 4; nt++) oacc[mt][nt][i] *= alpha;
      }
    }

    // P: C-layout regs -> LDS -> A-layout (wave-private; DS ops in-order per wave)
#pragma unroll
    for (int mt = 0; mt < 2; mt++)
#pragma unroll
      for (int nt = 0; nt < 8; nt++)
#pragma unroll
        for (int i = 0; i < 4; i++)
          Pl[w][mt * 16 + quad * 4 + i][nt * 16 + r] = f2bf(sacc[mt][nt][i]);

    // O += P @ V
#pragma unroll
    for (int ks = 0; ks < 4; ks++) {
#pragma unroll
      for (int mt = 0; mt < 2; mt++) {
        bf16x8 pf = *(const bf16x8*)&Pl[w][mt * 16 + r][ks * 32 + quad * 8];
#pragma unroll
        for (int nt = 0; nt < 4; nt++) {
          bf16x8 vf = *(const bf16x8*)&Vt[nt * 16 + r][ks * 32 + quad * 8];
          oacc[mt][nt] = __builtin_amdgcn_mfma_f32_16x16x32_bf16(pf, vf, oacc[mt][nt], 0, 0, 0);
        }
      }
    }
  }

  // epilogue: o[b][n][h*64+d] bf16
  int bb = bh >> 4, hh = bh & 15;
#pragma unroll
  for (int mt = 0; mt < 2; mt++)
#pragma unroll
    for (int nt = 0; nt < 4; nt++)
#pragma unroll
      for (int i = 0; i < 4; i++) {
        int row = qt * 128 + w * 32 + mt * 16 + quad * 4 + i;
        int d = nt * 16 + r;
        float v = oacc[mt][nt][i] / lst[mt][i];
        ob[((size_t)bb * N_ + row) * C_ + hh * D_ + d] = f2bf(v);
      }
}

// ------------------------------------ launch ---------------------------------------
extern "C" void kernel_launch(void* const* d_in, const int* in_sizes, int n_in,
                              void* d_out, int out_size, void* d_ws, size_t ws_size,
                              hipStream_t stream) {
  const float* x     = (const float*)d_in[0];
  const float* ln1g  = (const float*)d_in[1];
  const float* ln1b  = (const float*)d_in[2];
  const float* wqkv  = (const float*)d_in[3];   // [1024][3072]
  const float* wproj = (const float*)d_in[4];   // [1024][1024]
  const float* bproj = (const float*)d_in[5];
  const float* ln2g  = (const float*)d_in[6];
  const float* ln2b  = (const float*)d_in[7];
  const float* wfc1  = (const float*)d_in[8];   // [1024][4096]
  const float* bfc1  = (const float*)d_in[9];
  const float* wfc2  = (const float*)d_in[10];  // [4096][1024]
  const float* bfc2  = (const float*)d_in[11];
  float* out = (float*)d_out;

  const size_t MB = 1u << 20;
  if (ws_size < 88 * MB) return;  // layout below needs 88 MB
  char* w = (char*)d_ws;
  unsigned short* xn    = (unsigned short*)(w + 0 * MB);   // 8 MB
  unsigned short* qbuf  = (unsigned short*)(w + 8 * MB);   // 8 MB
  unsigned short* kbuf  = (unsigned short*)(w + 16 * MB);  // 8 MB
  unsigned short* vbuf  = (unsigned short*)(w + 24 * MB);  // 8 MB
  unsigned short* hbuf  = (unsigned short*)(w + 0 * MB);   // 32 MB, aliases xn/q/k/v (dead)
  unsigned short* obuf  = (unsigned short*)(w + 32 * MB);  // 8 MB
  float*          x2    = (float*)         (w + 40 * MB);  // 16 MB
  unsigned short* xn2   = (unsigned short*)(w + 56 * MB);  // 8 MB
  unsigned short* wqkvt = (unsigned short*)(w + 64 * MB);  // 6 MB
  unsigned short* wprjt = (unsigned short*)(w + 70 * MB);  // 2 MB
  unsigned short* wfc1t = (unsigned short*)(w + 72 * MB);  // 8 MB
  unsigned short* wfc2t = (unsigned short*)(w + 80 * MB);  // 8 MB

  dim3 tb(32, 8);
  ln_kernel<<<M_, 256, 0, stream>>>(x, ln1g, ln1b, xn);
  wtrans_kernel<<<dim3(3 * C_ / 32, C_ / 32), tb, 0, stream>>>(wqkv, wqkvt, C_, 3 * C_);
  wtrans_kernel<<<dim3(C_ / 32, C_ / 32), tb, 0, stream>>>(wproj, wprjt, C_, C_);
  wtrans_kernel<<<dim3(HID_ / 32, C_ / 32), tb, 0, stream>>>(wfc1, wfc1t, C_, HID_);
  wtrans_kernel<<<dim3(C_ / 32, HID_ / 32), tb, 0, stream>>>(wfc2, wfc2t, HID_, C_);

  gemm_kernel<0><<<dim3(3 * C_ / 128, M_ / 128), 256, 0, stream>>>(
      xn, wqkvt, nullptr, nullptr, nullptr, qbuf, kbuf, vbuf, M_, 3 * C_, C_);
  attn_kernel<<<B_ * H_ * (N_ / 128), 256, 0, stream>>>(qbuf, kbuf, vbuf, obuf);
  gemm_kernel<1><<<dim3(C_ / 128, M_ / 128), 256, 0, stream>>>(
      obuf, wprjt, bproj, x, x2, nullptr, nullptr, nullptr, M_, C_, C_);
  ln_kernel<<<M_, 256, 0, stream>>>(x2, ln2g, ln2b, xn2);
  gemm_kernel<2><<<dim3(HID_ / 128, M_ / 128), 256, 0, stream>>>(
      xn2, wfc1t, bfc1, nullptr, nullptr, hbuf, nullptr, nullptr, M_, HID_, C_);
  gemm_kernel<1><<<dim3(C_ / 128, M_ / 128), 256, 0, stream>>>(
      hbuf, wfc2t, bfc2, x2, out, nullptr, nullptr, nullptr, M_, C_, HID_);
}